// Round 9
// baseline (613.065 us; speedup 1.0000x reference)
//
#include <hip/hip_runtime.h>

typedef unsigned short ushort_t;
typedef __attribute__((ext_vector_type(8))) short s8v;
typedef __attribute__((ext_vector_type(4))) float f4v;

__device__ __forceinline__ float b2f(ushort_t h) {
    union { unsigned u; float f; } c; c.u = ((unsigned)h) << 16; return c.f;
}
__device__ __forceinline__ ushort_t f2b(float f) {
    union { float f; unsigned u; } c; c.f = f;
    unsigned u = c.u;
    return (ushort_t)((u + 0x7fffu + ((u >> 16) & 1u)) >> 16);
}

__device__ __forceinline__ void glds16(const void* g, void* l) {
    __builtin_amdgcn_global_load_lds(
        (const __attribute__((address_space(1))) void*)g,
        (__attribute__((address_space(3))) void*)l, 16, 0, 0);
}

// ---------------- weight transpose f32 [K,N] -> bf16 [N,K] ----------------
__global__ __launch_bounds__(256) void trans_k(const float* __restrict__ W,
                                               ushort_t* __restrict__ Wt,
                                               int K, int N) {
    __shared__ float tile[64][65];
    int k0 = blockIdx.x * 64, n0 = blockIdx.y * 64;
    int t = threadIdx.x;
    int c = t & 63, r4 = t >> 6;
#pragma unroll
    for (int i = 0; i < 16; ++i) {
        int r = i * 4 + r4;
        tile[r][c] = W[(size_t)(k0 + r) * N + n0 + c];
    }
    __syncthreads();
#pragma unroll
    for (int i = 0; i < 16; ++i) {
        int r = i * 4 + r4;
        Wt[(size_t)(n0 + r) * K + k0 + c] = f2b(tile[c][r]);
    }
}

// ---------------- norm: alpha*(x-mu)/(std_ddof1+eps)+bias -> bf16 --------
__global__ __launch_bounds__(256) void norm_k(const float* __restrict__ x,
                                              const float* __restrict__ al,
                                              const float* __restrict__ be,
                                              ushort_t* __restrict__ out) {
    int row = blockIdx.x;
    const float4* xr = (const float4*)(x + (size_t)row * 1024);
    float4 v = xr[threadIdx.x];
    float s = v.x + v.y + v.z + v.w;
    float q = v.x * v.x + v.y * v.y + v.z * v.z + v.w * v.w;
#pragma unroll
    for (int o = 32; o > 0; o >>= 1) {
        s += __shfl_down(s, o);
        q += __shfl_down(q, o);
    }
    __shared__ float ss[4], qq[4];
    int lane = threadIdx.x & 63, wv = threadIdx.x >> 6;
    if (lane == 0) { ss[wv] = s; qq[wv] = q; }
    __syncthreads();
    s = ss[0] + ss[1] + ss[2] + ss[3];
    q = qq[0] + qq[1] + qq[2] + qq[3];
    float mu = s * (1.f / 1024.f);
    float var = (q - 1024.f * mu * mu) * (1.f / 1023.f);
    var = fmaxf(var, 0.f);
    float inv = 1.f / (sqrtf(var) + 1e-6f);
    float4 a4 = ((const float4*)al)[threadIdx.x];
    float4 b4 = ((const float4*)be)[threadIdx.x];
    ushort4 o4;
    o4.x = f2b(a4.x * (v.x - mu) * inv + b4.x);
    o4.y = f2b(a4.y * (v.y - mu) * inv + b4.y);
    o4.z = f2b(a4.z * (v.z - mu) * inv + b4.z);
    o4.w = f2b(a4.w * (v.w - mu) * inv + b4.w);
    ((ushort4*)(out + (size_t)row * 1024))[threadIdx.x] = o4;
}

// ------- fused GLU+mask+lightconv: out = conv3(a*sigmoid(b)*m) -----------
__global__ __launch_bounds__(256) void gluconv_k(const ushort_t* __restrict__ t1,
                                                 const int* __restrict__ mask,
                                                 const float* __restrict__ cw,
                                                 ushort_t* __restrict__ out) {
    int i = blockIdx.x * 256 + threadIdx.x;
    int row = i >> 7;            // b*1024 + s
    int cc = (i & 127) << 3;
    int b = row >> 10, s = row & 1023;
    int head = cc >> 6;
    float w0 = cw[head * 3 + 0], w1 = cw[head * 3 + 1], w2 = cw[head * 3 + 2];
    float mx = fmaxf(w0, fmaxf(w1, w2));
    float e0 = __expf(w0 - mx), e1 = __expf(w1 - mx), e2 = __expf(w2 - mx);
    float inv = 1.f / (e0 + e1 + e2);
    float wt[3] = {e0 * inv, e1 * inv, e2 * inv};
    float a8[8] = {0.f, 0.f, 0.f, 0.f, 0.f, 0.f, 0.f, 0.f};
#pragma unroll
    for (int tap = 0; tap < 3; ++tap) {
        int ss = s + tap - 1;
        if (ss < 0 || ss > 1023) continue;
        float wm = (mask[b * 1024 + ss] == 0) ? 0.f : wt[tap];
        size_t base = (size_t)(row + tap - 1) * 2048 + cc;
        s8v va = *(const s8v*)(t1 + base);
        s8v vb = *(const s8v*)(t1 + base + 1024);
#pragma unroll
        for (int j = 0; j < 8; ++j) {
            float a = b2f((ushort_t)va[j]);
            float xx = b2f((ushort_t)vb[j]);
            float sg = 1.f / (1.f + __expf(-xx));
            a8[j] += wm * a * sg;
        }
    }
    s8v ov;
#pragma unroll
    for (int j = 0; j < 8; ++j) ov[j] = (short)f2b(a8[j]);
    *(s8v*)(out + (size_t)row * 1024 + cc) = ov;
}

// ---------------- bf16 GEMM, 128x256 tile, BK=32, ring-3, 2 blocks/CU ----
// A [M,K] bf16 rm; Bt [N,K] bf16 rm. 512 threads = 8 waves (2M x 4N),
// per-wave output 64x64 -> acc 4x4 f4v = 64 regs; total <=128 regs/wave
// (launch_bounds(512,4)) => 2 blocks/CU (LDS 72KB x2 = 144KB, 16 waves).
// LDS: ring-3 x 24KB {A 128x32 (8KB), B 256x32 (16KB)}, proven 0-conflict
// slot-XOR swizzle. Per tile: stage i+2 (3 glds16, distance-2 = full-tile
// HBM lead) -> 8 ds_reads -> 16 MFMA (setprio) -> lgkmcnt(0), vmcnt(3)
// (= tile i+1 landed; counted, never 0), barrier. Inter-block slip covers
// the fence stalls (m97/m114 mechanism).
// EPI: 0 = bf16 out (+bias); 1 = f32 out (+bias+res); 2 = bf16 relu(+bias)
template <int EPI>
__global__ __launch_bounds__(512, 4) void gemm_k(const ushort_t* __restrict__ A,
                                                 const ushort_t* __restrict__ Bt,
                                                 const float* __restrict__ bias,
                                                 const float* res, float* outf,
                                                 ushort_t* outb, int N, int K) {
    __shared__ char smem[73728] __attribute__((aligned(128)));
    const int NBN = N >> 8;
    const int nwg = gridDim.x;
    const int per = nwg >> 3;
    const int tt = (blockIdx.x & 7) * per + (blockIdx.x >> 3);  // XCD strips
    const int gw = NBN << 4;            // GROUP_M = 16
    const int g = tt / gw;
    const int rem = tt - g * gw;
    const int bm = (g << 4) + (rem & 15);
    const int bn = rem >> 4;

    const int t = threadIdx.x;
    const int l = t & 63, w = t >> 6;
    const int wm = w >> 2, wn = w & 3;
    const int lr = l & 15, lk = l >> 4;

    // staging: linear LDS dest, inverse-swizzled global source slot
    const int swzel = (((t & 3) ^ ((t >> 3) & 3)) << 3);
    const int r0 = t >> 2;
    const ushort_t* pA0 = A + (size_t)(bm * 128 + r0) * K + swzel;
    const ushort_t* pB0 = Bt + (size_t)(bn * 256 + r0) * K + swzel;
    const ushort_t* pB1 = pB0 + (size_t)128 * K;

    // fragment ds_read offsets: 16-row x 4-slot, conflict-free
    const int fswz = ((lk ^ ((lr >> 1) & 3)) << 4);
    int aoff[4], boff[4];
#pragma unroll
    for (int m = 0; m < 4; ++m)
        aoff[m] = (wm * 64 + m * 16 + lr) * 64 + fswz;
#pragma unroll
    for (int n = 0; n < 4; ++n)
        boff[n] = 8192 + (wn * 64 + n * 16 + lr) * 64 + fswz;

    f4v acc[4][4];
#pragma unroll
    for (int m = 0; m < 4; ++m)
#pragma unroll
        for (int n = 0; n < 4; ++n) acc[m][n] = f4v{0.f, 0.f, 0.f, 0.f};

    const int NK = K >> 5;  // >= 32

    // ---- prologue: stage tile 0 -> buf0, tile 1 -> buf1 ----
    {
        char* d0 = smem + t * 16;
        glds16(pA0 + 0, d0);
        glds16(pB0 + 0, d0 + 8192);
        glds16(pB1 + 0, d0 + 16384);
        char* d1 = smem + 24576 + t * 16;
        glds16(pA0 + 32, d1);
        glds16(pB0 + 32, d1 + 8192);
        glds16(pB1 + 32, d1 + 16384);
    }
    asm volatile("s_waitcnt vmcnt(3)");   // tile 0 landed
    __builtin_amdgcn_s_barrier();
    __builtin_amdgcn_sched_barrier(0);

    int cur = 0;
    for (int i = 0; i < NK; ++i) {
        const char* cb = smem + cur;
        int nx2 = cur + 49152; if (nx2 >= 73728) nx2 -= 73728;  // buf (i+2)%3
        int st = i + 2; if (st >= NK) st = NK - 1;              // uniform tail
        const int ko = st * 32;
        char* sd = smem + nx2 + t * 16;

        // stage tile i+2 (issued early; waited 2 fences later)
        glds16(pA0 + ko, sd);
        glds16(pB0 + ko, sd + 8192);
        glds16(pB1 + ko, sd + 16384);

        // read this tile's fragments; MFMA
        s8v aF[4], bF[4];
#pragma unroll
        for (int m = 0; m < 4; ++m) aF[m] = *(const s8v*)(cb + aoff[m]);
#pragma unroll
        for (int n = 0; n < 4; ++n) bF[n] = *(const s8v*)(cb + boff[n]);
        __builtin_amdgcn_s_setprio(1);
#pragma unroll
        for (int m = 0; m < 4; ++m)
#pragma unroll
            for (int n = 0; n < 4; ++n)
                acc[m][n] = __builtin_amdgcn_mfma_f32_16x16x32_bf16(
                    aF[m], bF[n], acc[m][n], 0, 0, 0);
        __builtin_amdgcn_s_setprio(0);

        __builtin_amdgcn_sched_barrier(0);
        asm volatile("s_waitcnt lgkmcnt(0)");
        asm volatile("s_waitcnt vmcnt(3)");   // tile i+1 landed (counted)
        __builtin_amdgcn_s_barrier();
        __builtin_amdgcn_sched_barrier(0);

        cur += 24576; if (cur >= 73728) cur = 0;
    }

    asm volatile("s_waitcnt vmcnt(0)");       // drain tail stages
    __builtin_amdgcn_s_barrier();

    // ---------------- epilogue ----------------
    // C/D layout (16x16): col = lane&15, row = (lane>>4)*4 + reg
    if (EPI == 1) {
#pragma unroll
        for (int n = 0; n < 4; ++n) {
            int gcol = bn * 256 + wn * 64 + n * 16 + lr;
            float bb = bias[gcol];
#pragma unroll
            for (int m = 0; m < 4; ++m) {
#pragma unroll
                for (int r = 0; r < 4; ++r) {
                    int grow = bm * 128 + wm * 64 + m * 16 + lk * 4 + r;
                    size_t oi = (size_t)grow * N + gcol;
                    outf[oi] = acc[m][n][r] + bb + res[oi];
                }
            }
        }
    } else {
        float bb4[4];
#pragma unroll
        for (int n = 0; n < 4; ++n)
            bb4[n] = bias[bn * 256 + wn * 64 + n * 16 + lr];
        // acc -> smem [128 rows][512 B], col-bytes XOR ((row&3)<<4) (64KB)
#pragma unroll
        for (int m = 0; m < 4; ++m)
#pragma unroll
            for (int n = 0; n < 4; ++n)
#pragma unroll
                for (int r = 0; r < 4; ++r) {
                    int row = wm * 64 + m * 16 + lk * 4 + r;
                    int colb = ((wn * 64 + n * 16 + lr) * 2) ^ ((row & 3) << 4);
                    float v = acc[m][n][r] + bb4[n];
                    if (EPI == 2) v = fmaxf(v, 0.f);
                    *(ushort_t*)(smem + row * 512 + colb) = f2b(v);
                }
        __builtin_amdgcn_s_barrier();
        // coalesced 16B readout: 8 iters x 16 rows
#pragma unroll
        for (int s = 0; s < 8; ++s) {
            int row = s * 16 + (t >> 5);
            int byt = row * 512 + (((t & 31) * 16) ^ ((row & 3) << 4));
            int grow = bm * 128 + row;
            int gcol = bn * 256 + (t & 31) * 8;
            *(s8v*)(outb + (size_t)grow * N + gcol) = *(const s8v*)(smem + byt);
        }
    }
}

extern "C" void kernel_launch(void* const* d_in, const int* in_sizes, int n_in,
                              void* d_out, int out_size, void* d_ws, size_t ws_size,
                              hipStream_t stream) {
    const float* x      = (const float*)d_in[0];
    const int*   mask   = (const int*)d_in[1];
    const float* alpha1 = (const float*)d_in[2];
    const float* bias1  = (const float*)d_in[3];
    const float* alpha2 = (const float*)d_in[4];
    const float* bias2  = (const float*)d_in[5];
    const float* W_l1   = (const float*)d_in[6];
    const float* b_l1   = (const float*)d_in[7];
    const float* conv_w = (const float*)d_in[8];
    const float* W_l2   = (const float*)d_in[9];
    const float* b_l2   = (const float*)d_in[10];
    const float* W_ff1  = (const float*)d_in[11];
    const float* b_ff1  = (const float*)d_in[12];
    const float* W_ff2  = (const float*)d_in[13];
    const float* b_ff2  = (const float*)d_in[14];
    float* out = (float*)d_out;

    char* ws = (char*)d_ws;
    size_t off = 0;
    auto alloc = [&](size_t b) {
        char* p = ws + off;
        off += (b + 255) & ~(size_t)255;
        return p;
    };
    ushort_t* Wl1t  = (ushort_t*)alloc(2048ull * 1024 * 2);
    ushort_t* Wl2t  = (ushort_t*)alloc(1024ull * 1024 * 2);
    ushort_t* Wff1t = (ushort_t*)alloc(4096ull * 1024 * 2);
    ushort_t* Wff2t = (ushort_t*)alloc(1024ull * 4096 * 2);
    char* regA = alloc(134217728ull);             // t1 / ffn1-out
    ushort_t* B1 = (ushort_t*)alloc(33554432ull); // h1 / h2
    ushort_t* C1 = (ushort_t*)alloc(33554432ull); // conv-out
    ushort_t* t1 = (ushort_t*)regA;
    ushort_t* f1 = (ushort_t*)regA;

    const int R = 16384;  // B*S rows

    trans_k<<<dim3(16, 32), 256, 0, stream>>>(W_l1, Wl1t, 1024, 2048);
    trans_k<<<dim3(16, 16), 256, 0, stream>>>(W_l2, Wl2t, 1024, 1024);
    trans_k<<<dim3(16, 64), 256, 0, stream>>>(W_ff1, Wff1t, 1024, 4096);
    trans_k<<<dim3(64, 16), 256, 0, stream>>>(W_ff2, Wff2t, 4096, 1024);

    // sublayer 1: norm -> GEMM(D,2D)+bias -> fused GLU*mask+conv -> GEMM+res
    norm_k<<<R, 256, 0, stream>>>(x, alpha1, bias1, B1);
    gemm_k<0><<<128 * 8, 512, 0, stream>>>(B1, Wl1t, b_l1, nullptr, nullptr, t1, 2048, 1024);
    gluconv_k<<<8192, 256, 0, stream>>>(t1, mask, conv_w, C1);
    gemm_k<1><<<128 * 4, 512, 0, stream>>>(C1, Wl2t, b_l2, x, out, nullptr, 1024, 1024);

    // sublayer 2: norm -> GEMM(D,DFF)+bias+relu -> GEMM(DFF,D)+bias+res
    norm_k<<<R, 256, 0, stream>>>(out, alpha2, bias2, B1);
    gemm_k<2><<<128 * 16, 512, 0, stream>>>(B1, Wff1t, b_ff1, nullptr, nullptr, f1, 4096, 1024);
    gemm_k<1><<<128 * 4, 512, 0, stream>>>(f1, Wff2t, b_ff2, out, out, nullptr, 1024, 4096);
}

// Round 10
// 549.027 us; speedup vs baseline: 1.1166x; 1.1166x over previous
//
#include <hip/hip_runtime.h>

typedef unsigned short ushort_t;
typedef __attribute__((ext_vector_type(8))) short s8v;
typedef __attribute__((ext_vector_type(4))) float f4v;

__device__ __forceinline__ float b2f(ushort_t h) {
    union { unsigned u; float f; } c; c.u = ((unsigned)h) << 16; return c.f;
}
__device__ __forceinline__ ushort_t f2b(float f) {
    union { float f; unsigned u; } c; c.f = f;
    unsigned u = c.u;
    return (ushort_t)((u + 0x7fffu + ((u >> 16) & 1u)) >> 16);
}

__device__ __forceinline__ void glds16(const void* g, void* l) {
    __builtin_amdgcn_global_load_lds(
        (const __attribute__((address_space(1))) void*)g,
        (__attribute__((address_space(3))) void*)l, 16, 0, 0);
}

// ---------------- weight transpose f32 [K,N] -> bf16 [N,K] ----------------
// PERM=1 (W_l1 only): dest row for source col s interleaves GLU pairs:
//   s<1024 (a): d = (s>>7)*256 + (s&127)
//   s>=1024 (b): d = ((s-1024)>>7)*256 + 128 + (s&127)
// so a 256-row block of Wt = [a-block 128 | b-block 128] with matching cols.
template <int PERM>
__global__ __launch_bounds__(256) void trans_k(const float* __restrict__ W,
                                               ushort_t* __restrict__ Wt,
                                               int K, int N) {
    __shared__ float tile[64][65];
    int k0 = blockIdx.x * 64, n0 = blockIdx.y * 64;
    int t = threadIdx.x;
    int c = t & 63, r4 = t >> 6;
#pragma unroll
    for (int i = 0; i < 16; ++i) {
        int r = i * 4 + r4;
        tile[r][c] = W[(size_t)(k0 + r) * N + n0 + c];
    }
    __syncthreads();
#pragma unroll
    for (int i = 0; i < 16; ++i) {
        int r = i * 4 + r4;
        int s = n0 + r;
        int d;
        if (PERM) {
            int a = (s < 1024);
            int s2 = a ? s : s - 1024;
            d = ((s2 >> 7) << 8) + (a ? 0 : 128) + (s2 & 127);
        } else {
            d = s;
        }
        Wt[(size_t)d * K + k0 + c] = f2b(tile[c][r]);
    }
}

// ---------------- norm: alpha*(x-mu)/(std_ddof1+eps)+bias -> bf16 --------
__global__ __launch_bounds__(256) void norm_k(const float* __restrict__ x,
                                              const float* __restrict__ al,
                                              const float* __restrict__ be,
                                              ushort_t* __restrict__ out) {
    int row = blockIdx.x;
    const float4* xr = (const float4*)(x + (size_t)row * 1024);
    float4 v = xr[threadIdx.x];
    float s = v.x + v.y + v.z + v.w;
    float q = v.x * v.x + v.y * v.y + v.z * v.z + v.w * v.w;
#pragma unroll
    for (int o = 32; o > 0; o >>= 1) {
        s += __shfl_down(s, o);
        q += __shfl_down(q, o);
    }
    __shared__ float ss[4], qq[4];
    int lane = threadIdx.x & 63, wv = threadIdx.x >> 6;
    if (lane == 0) { ss[wv] = s; qq[wv] = q; }
    __syncthreads();
    s = ss[0] + ss[1] + ss[2] + ss[3];
    q = qq[0] + qq[1] + qq[2] + qq[3];
    float mu = s * (1.f / 1024.f);
    float var = (q - 1024.f * mu * mu) * (1.f / 1023.f);
    var = fmaxf(var, 0.f);
    float inv = 1.f / (sqrtf(var) + 1e-6f);
    float4 a4 = ((const float4*)al)[threadIdx.x];
    float4 b4 = ((const float4*)be)[threadIdx.x];
    ushort4 o4;
    o4.x = f2b(a4.x * (v.x - mu) * inv + b4.x);
    o4.y = f2b(a4.y * (v.y - mu) * inv + b4.y);
    o4.z = f2b(a4.z * (v.z - mu) * inv + b4.z);
    o4.w = f2b(a4.w * (v.w - mu) * inv + b4.w);
    ((ushort4*)(out + (size_t)row * 1024))[threadIdx.x] = o4;
}

// ---------------- depthwise lightconv K=3, softmax weights ----------------
// reads g (GLU+mask already applied), writes conv output
__global__ __launch_bounds__(256) void conv_k(const ushort_t* __restrict__ g,
                                              const float* __restrict__ cw,
                                              ushort_t* __restrict__ out) {
    int i = blockIdx.x * 256 + threadIdx.x;
    int row = i >> 7;
    int cc = (i & 127) << 3;
    int s = row & 1023;
    int head = cc >> 6;
    float w0 = cw[head * 3 + 0], w1 = cw[head * 3 + 1], w2 = cw[head * 3 + 2];
    float mx = fmaxf(w0, fmaxf(w1, w2));
    float e0 = __expf(w0 - mx), e1 = __expf(w1 - mx), e2 = __expf(w2 - mx);
    float inv = 1.f / (e0 + e1 + e2);
    w0 = e0 * inv; w1 = e1 * inv; w2 = e2 * inv;
    size_t base = (size_t)row * 1024 + cc;
    s8v z = {0, 0, 0, 0, 0, 0, 0, 0};
    s8v vm = (s > 0)    ? *(const s8v*)(g + base - 1024) : z;
    s8v v0 = *(const s8v*)(g + base);
    s8v vp = (s < 1023) ? *(const s8v*)(g + base + 1024) : z;
    s8v ov;
#pragma unroll
    for (int j = 0; j < 8; ++j) {
        float r = w0 * b2f((ushort_t)vm[j]) + w1 * b2f((ushort_t)v0[j]) +
                  w2 * b2f((ushort_t)vp[j]);
        ov[j] = (short)f2b(r);
    }
    *(s8v*)(out + base) = ov;
}

// ---------------- bf16 GEMM, 256x256 tile, BK=32, 16x16x32 MFMA ----------
// r5 structure (measured best): ring-4 x 32KB LDS, proven 0-conflict
// slot-XOR swizzle; per tile: [aH reads | stage i+3 | MFMA low] SB vmcnt(6)
// barrier SB [next aL/bF reads | MFMA high]; ONE barrier + ONE counted
// vmcnt per tile.
// EPI: 1 = f32 out (+bias+res); 2 = bf16 relu(+bias);
//      3 = GLU: pairs cols (a=local<128, b=local>=128) of the PERM-interleaved
//          W_l1 output, writes g = a*sigmoid(b)*mask, bf16 [M, N/2].
template <int EPI>
__global__ __launch_bounds__(512, 1) void gemm_k(const ushort_t* __restrict__ A,
                                                 const ushort_t* __restrict__ Bt,
                                                 const float* __restrict__ bias,
                                                 const int* __restrict__ maskp,
                                                 const float* res, float* outf,
                                                 ushort_t* outb, int N, int K) {
    __shared__ char smem[131072] __attribute__((aligned(128)));
    const int NBN = N >> 8;
    const int nwg = gridDim.x;
    const int per = nwg >> 3;
    const int tt = (blockIdx.x & 7) * per + (blockIdx.x >> 3);  // XCD strips
    const int gw = NBN << 3;            // GROUP_M = 8
    const int g = tt / gw;
    const int rem = tt - g * gw;
    const int bm = (g << 3) + (rem & 7);
    const int bn = rem >> 3;

    const int t = threadIdx.x;
    const int l = t & 63, w = t >> 6;
    const int wm = w >> 2, wn = w & 3;
    const int lr = l & 15, lk = l >> 4;

    // staging: linear LDS dest, inverse-swizzled global source slot
    const int swzel = (((t & 3) ^ ((t >> 3) & 3)) << 3);
    const int r0 = t >> 2;
    const ushort_t* pA0 = A + (size_t)(bm * 256 + r0) * K + swzel;
    const ushort_t* pA1 = pA0 + (size_t)128 * K;
    const ushort_t* pB0 = Bt + (size_t)(bn * 256 + r0) * K + swzel;
    const ushort_t* pB1 = pB0 + (size_t)128 * K;

    // fragment ds_read offsets: 16-row x 4-slot, conflict-free
    const int fswz = ((lk ^ ((lr >> 1) & 3)) << 4);
    int aoff[8], boff[4];
#pragma unroll
    for (int m = 0; m < 8; ++m)
        aoff[m] = (wm * 128 + m * 16 + lr) * 64 + fswz;
#pragma unroll
    for (int n = 0; n < 4; ++n)
        boff[n] = 16384 + (wn * 64 + n * 16 + lr) * 64 + fswz;

    f4v acc[8][4];
#pragma unroll
    for (int m = 0; m < 8; ++m)
#pragma unroll
        for (int n = 0; n < 4; ++n) acc[m][n] = f4v{0.f, 0.f, 0.f, 0.f};

    const int NK = K >> 5;

    // ---- prologue: stage tiles 0,1,2 ----
#pragma unroll
    for (int p = 0; p < 3; ++p) {
        char* d = smem + p * 32768 + t * 16;
        glds16(pA0 + p * 32, d);
        glds16(pA1 + p * 32, d + 8192);
        glds16(pB0 + p * 32, d + 16384);
        glds16(pB1 + p * 32, d + 24576);
    }
    asm volatile("s_waitcnt vmcnt(8)");        // tile 0 landed
    __builtin_amdgcn_s_barrier();
    __builtin_amdgcn_sched_barrier(0);

    s8v aL0[4], bF0[4], aL1[4], bF1[4], aH[4];
#pragma unroll
    for (int m = 0; m < 4; ++m) aL0[m] = *(const s8v*)(smem + aoff[m]);
#pragma unroll
    for (int n = 0; n < 4; ++n) bF0[n] = *(const s8v*)(smem + boff[n]);

#define KSTEP(I, CAL, CBF, NAL, NBF)                                           \
    {                                                                          \
        const int i_ = (I);                                                    \
        const char* cb_ = smem + (size_t)(i_ & 3) * 32768;                     \
        const char* nb_ = smem + (size_t)((i_ + 1) & 3) * 32768;               \
        int st_ = i_ + 3; if (st_ >= NK) st_ = NK - 1;                         \
        char* sd_ = smem + (size_t)((i_ + 3) & 3) * 32768 + t * 16;            \
        const int ko_ = st_ * 32;                                              \
        /* segment 1: aH reads | stage | MFMA low (free interleave) */         \
        _Pragma("unroll")                                                      \
        for (int m = 0; m < 4; ++m) aH[m] = *(const s8v*)(cb_ + aoff[4 + m]);  \
        glds16(pA0 + ko_, sd_);                                                \
        glds16(pA1 + ko_, sd_ + 8192);                                         \
        glds16(pB0 + ko_, sd_ + 16384);                                        \
        glds16(pB1 + ko_, sd_ + 24576);                                        \
        __builtin_amdgcn_s_setprio(1);                                         \
        _Pragma("unroll")                                                      \
        for (int m = 0; m < 4; ++m)                                            \
            _Pragma("unroll")                                                  \
            for (int n = 0; n < 4; ++n)                                        \
                acc[m][n] = __builtin_amdgcn_mfma_f32_16x16x32_bf16(           \
                    CAL[m], CBF[n], acc[m][n], 0, 0, 0);                       \
        __builtin_amdgcn_s_setprio(0);                                         \
        __builtin_amdgcn_sched_barrier(0);                                     \
        asm volatile("s_waitcnt vmcnt(6)");   /* tile i+1 landed */            \
        __builtin_amdgcn_s_barrier();                                          \
        __builtin_amdgcn_sched_barrier(0);                                     \
        /* segment 2: next-tile aL/bF reads | MFMA high (free interleave) */   \
        _Pragma("unroll")                                                      \
        for (int m = 0; m < 4; ++m) NAL[m] = *(const s8v*)(nb_ + aoff[m]);     \
        _Pragma("unroll")                                                      \
        for (int n = 0; n < 4; ++n) NBF[n] = *(const s8v*)(nb_ + boff[n]);     \
        __builtin_amdgcn_s_setprio(1);                                         \
        _Pragma("unroll")                                                      \
        for (int m = 0; m < 4; ++m)                                            \
            _Pragma("unroll")                                                  \
            for (int n = 0; n < 4; ++n)                                        \
                acc[4 + m][n] = __builtin_amdgcn_mfma_f32_16x16x32_bf16(       \
                    aH[m], CBF[n], acc[4 + m][n], 0, 0, 0);                    \
        __builtin_amdgcn_s_setprio(0);                                         \
    }

    for (int ii = 0; ii < NK; ii += 2) {
        KSTEP(ii, aL0, bF0, aL1, bF1);
        KSTEP(ii + 1, aL1, bF1, aL0, bF0);
    }
#undef KSTEP

    // ---------------- epilogue ----------------
    // C/D layout (16x16): col = lane&15, row = (lane>>4)*4 + reg
    if (EPI == 1) {
#pragma unroll
        for (int n = 0; n < 4; ++n) {
            int gcol = bn * 256 + wn * 64 + n * 16 + lr;
            float bb = bias[gcol];
#pragma unroll
            for (int m = 0; m < 8; ++m) {
#pragma unroll
                for (int r = 0; r < 4; ++r) {
                    int grow = bm * 256 + wm * 128 + m * 16 + lk * 4 + r;
                    size_t oi = (size_t)grow * N + gcol;
                    outf[oi] = acc[m][n][r] + bb + res[oi];
                }
            }
        }
    } else {
        asm volatile("s_waitcnt vmcnt(0)" ::: "memory");  // drain tail stages
        __builtin_amdgcn_s_barrier();
        float bb4[4];
#pragma unroll
        for (int n = 0; n < 4; ++n) {
            int d = bn * 256 + wn * 64 + n * 16 + lr;
            int src = d;
            if (EPI == 3)  // un-permute: bias index in original W_l1 space
                src = ((d >> 8) << 7) + (d & 127) + (((d >> 7) & 1) << 10);
            bb4[n] = bias[src];
        }
        // acc -> smem [256 rows][512 B], col-bytes XOR ((row&3)<<4)
#pragma unroll
        for (int m = 0; m < 8; ++m)
#pragma unroll
            for (int n = 0; n < 4; ++n)
#pragma unroll
                for (int r = 0; r < 4; ++r) {
                    int row = wm * 128 + m * 16 + lk * 4 + r;
                    int colb = ((wn * 64 + n * 16 + lr) * 2) ^ ((row & 3) << 4);
                    float v = acc[m][n][r] + bb4[n];
                    if (EPI == 2) v = fmaxf(v, 0.f);
                    *(ushort_t*)(smem + row * 512 + colb) = f2b(v);
                }
        __builtin_amdgcn_s_barrier();
        if (EPI == 3) {
            // GLU readout: a-chunk [0,256B), b-chunk +256B (same swizzle bits)
#pragma unroll
            for (int s = 0; s < 8; ++s) {
                int row = s * 32 + (t >> 4);
                int abyt = row * 512 + (((t & 15) * 16) ^ ((row & 3) << 4));
                s8v av = *(const s8v*)(smem + abyt);
                s8v bv = *(const s8v*)(smem + abyt + 256);
                int grow = bm * 256 + row;
                float mval =
                    (maskp[(grow >> 10) * 1024 + (grow & 1023)] == 0) ? 0.f : 1.f;
                s8v ov;
#pragma unroll
                for (int j = 0; j < 8; ++j) {
                    float a = b2f((ushort_t)av[j]);
                    float xx = b2f((ushort_t)bv[j]);
                    ov[j] = (short)f2b(a * mval / (1.f + __expf(-xx)));
                }
                *(s8v*)(outb + (size_t)grow * (N >> 1) + bn * 128 +
                        (t & 15) * 8) = ov;
            }
        } else {
            // coalesced 16B readout
#pragma unroll
            for (int s = 0; s < 16; ++s) {
                int row = s * 16 + (t >> 5);
                int byt = row * 512 + (((t & 31) * 16) ^ ((row & 3) << 4));
                int grow = bm * 256 + row;
                int gcol = bn * 256 + (t & 31) * 8;
                *(s8v*)(outb + (size_t)grow * N + gcol) =
                    *(const s8v*)(smem + byt);
            }
        }
    }
}

extern "C" void kernel_launch(void* const* d_in, const int* in_sizes, int n_in,
                              void* d_out, int out_size, void* d_ws, size_t ws_size,
                              hipStream_t stream) {
    const float* x      = (const float*)d_in[0];
    const int*   mask   = (const int*)d_in[1];
    const float* alpha1 = (const float*)d_in[2];
    const float* bias1  = (const float*)d_in[3];
    const float* alpha2 = (const float*)d_in[4];
    const float* bias2  = (const float*)d_in[5];
    const float* W_l1   = (const float*)d_in[6];
    const float* b_l1   = (const float*)d_in[7];
    const float* conv_w = (const float*)d_in[8];
    const float* W_l2   = (const float*)d_in[9];
    const float* b_l2   = (const float*)d_in[10];
    const float* W_ff1  = (const float*)d_in[11];
    const float* b_ff1  = (const float*)d_in[12];
    const float* W_ff2  = (const float*)d_in[13];
    const float* b_ff2  = (const float*)d_in[14];
    float* out = (float*)d_out;

    char* ws = (char*)d_ws;
    size_t off = 0;
    auto alloc = [&](size_t b) {
        char* p = ws + off;
        off += (b + 255) & ~(size_t)255;
        return p;
    };
    ushort_t* Wl1t  = (ushort_t*)alloc(2048ull * 1024 * 2);
    ushort_t* Wl2t  = (ushort_t*)alloc(1024ull * 1024 * 2);
    ushort_t* Wff1t = (ushort_t*)alloc(4096ull * 1024 * 2);
    ushort_t* Wff2t = (ushort_t*)alloc(1024ull * 4096 * 2);
    char* regA = alloc(134217728ull);             // g (16384x1024) / f1
    ushort_t* B1 = (ushort_t*)alloc(33554432ull); // h1 / h2
    ushort_t* C1 = (ushort_t*)alloc(33554432ull); // conv-out
    ushort_t* G1 = (ushort_t*)regA;               // GLU output (dead before f1)
    ushort_t* f1 = (ushort_t*)regA;

    const int R = 16384;  // B*S rows

    trans_k<1><<<dim3(16, 32), 256, 0, stream>>>(W_l1, Wl1t, 1024, 2048);
    trans_k<0><<<dim3(16, 16), 256, 0, stream>>>(W_l2, Wl2t, 1024, 1024);
    trans_k<0><<<dim3(16, 64), 256, 0, stream>>>(W_ff1, Wff1t, 1024, 4096);
    trans_k<0><<<dim3(64, 16), 256, 0, stream>>>(W_ff2, Wff2t, 4096, 1024);

    // sublayer 1: norm -> GEMM(D,2D)+bias+GLU+mask (fused) -> conv -> GEMM+res
    norm_k<<<R, 256, 0, stream>>>(x, alpha1, bias1, B1);
    gemm_k<3><<<64 * 8, 512, 0, stream>>>(B1, Wl1t, b_l1, mask, nullptr,
                                          nullptr, G1, 2048, 1024);
    conv_k<<<8192, 256, 0, stream>>>(G1, conv_w, C1);
    gemm_k<1><<<64 * 4, 512, 0, stream>>>(C1, Wl2t, b_l2, nullptr, x, out,
                                          nullptr, 1024, 1024);

    // sublayer 2: norm -> GEMM(D,DFF)+bias+relu -> GEMM(DFF,D)+bias+res
    norm_k<<<R, 256, 0, stream>>>(out, alpha2, bias2, B1);
    gemm_k<2><<<64 * 16, 512, 0, stream>>>(B1, Wff1t, b_ff1, nullptr, nullptr,
                                           nullptr, f1, 4096, 1024);
    gemm_k<1><<<64 * 4, 512, 0, stream>>>(f1, Wff2t, b_ff2, nullptr, out, out,
                                          nullptr, 1024, 4096);
}